// Round 12
// baseline (153.499 us; speedup 1.0000x reference)
//
#include <hip/hip_runtime.h>
#include <stdint.h>

#define SCORE_THRESH 0.05f
#define IOU_THRESH 0.5f
#define TOP_K 1000
#define MAX_DET 100

#define UBINS 4096             // 12-bit nonuniform bins on u=1-s (exp+5 mantissa)
#define NREP 4                 // replicated histograms (flush-contention relief)
#define CAND_CAP 2048
#define NMS_CHUNK 128          // rows per NMS staging chunk (dbuf: 2x128x16 u64 = 32KB)

typedef unsigned int u32;
typedef unsigned long long u64;

// ---- ws layout (bytes) ----
// [hist][state][bar] is one contiguous host-memset region.
#define OFF_HIST     0          // u32[NREP*4096] = 65536
#define OFF_STATE    65536      // 1024 -> 66560 (slot5 = cand_cnt at [5*32])
#define OFF_BAR      66560      // 4 barriers x 8192B (1024 flags + go) -> 99328
#define MEMSET_LEN   99328
#define OFF_CAND     99328      // u64[2048] = 16384 -> 115712 (full keys)
#define OFF_RFLAG    115712     // u32[1000] -> 119712
#define OFF_SIDX     119712     // u32[1000] -> 123712
#define OFF_SSCORE   123712     // float[1000] -> 127712
#define OFF_CBOX     127712     // float[4000] -> 143712 (16B aligned)
#define OFF_M        143712     // u64[1000*16] = 128000 -> 271712 (8B aligned)
#define OFF_SCORES   271712     // float[A]

#define BAR_STRIDE_U32 2048     // per barrier: flags[0..1023], go word at [1024]

__device__ __forceinline__ u32 order_f32(float f) {
    u32 b = __float_as_uint(f);
    return (b & 0x80000000u) ? ~b : (b | 0x80000000u);
}

// Distribution-matched 12-bit bin, ASCENDING in u=1-s (descending score).
// Exact for s in [0.5,1] (Sterbenz), monotone everywhere; exponent bits give
// log-scale tail resolution so ONE histogram pass resolves the top-1000 cut
// (cut bin holds ~31 anchors). Sentinel s0=-1 -> u=2.0 -> clamped 4095.
__device__ __forceinline__ u32 ubin(float s0) {
    float u = 1.0f - s0;
    u32 bin = __float_as_uint(u) >> 18;      // sign(0)+exp(8)+mantissa(5)
    return bin > (UBINS - 1) ? (UBINS - 1) : bin;
}

// MALL-direct (sc1) accessors: relaxed agent-scope atomics carry no fence ->
// no buffer_wbl2/buffer_inv ever. Stores write through to the coherence
// point; loads bypass stale caches.
__device__ __forceinline__ void st_sc(u32* p, u32 v)   { __hip_atomic_store(p, v, __ATOMIC_RELAXED, __HIP_MEMORY_SCOPE_AGENT); }
__device__ __forceinline__ void st_sc(float* p, float v){ __hip_atomic_store(p, v, __ATOMIC_RELAXED, __HIP_MEMORY_SCOPE_AGENT); }
__device__ __forceinline__ void st_sc(u64* p, u64 v)   { __hip_atomic_store(p, v, __ATOMIC_RELAXED, __HIP_MEMORY_SCOPE_AGENT); }
__device__ __forceinline__ u32  ld_sc(u32* p)          { return __hip_atomic_load(p, __ATOMIC_RELAXED, __HIP_MEMORY_SCOPE_AGENT); }

// Device-wide barrier v5 (R10/R11-proven): parallel flag arrival (1 sc1
// store per block, zero RMWs) + SINGLE sweeper (block 0) + one-line go-word
// poll for everyone else. nflags = number of arrivals to sweep.
// Ledger: R1 inv-storm 620; R2 tag-walks 271; R3/R7 counter-tree 98;
// R8 all-blocks-sweep 124; v5 -> 73/68.
// Correctness: __syncthreads + vmcnt(0) put this block's sc1 data stores at
// the coherence point before its flag store; readers first-touch data lines
// only after the producing barrier. Flags monotone 0->1, host-zeroed;
// non-waiting blocks race ahead/exit safely.
__device__ __forceinline__ void gbar(u32* barr, int k, int b, int nflags, bool dowait) {
    __syncthreads();
    u32* base = barr + (size_t)k * BAR_STRIDE_U32;
    if (threadIdx.x == 0) {
        asm volatile("s_waitcnt vmcnt(0)" ::: "memory");
        st_sc(&base[b], 1u);
    }
    if (!dowait) return;
    if (b == 0) {
        for (;;) {
            int my = 1;
            for (int i = (int)threadIdx.x; i < nflags; i += 256) my &= (int)ld_sc(&base[i]);
            if (__syncthreads_and(my)) break;
        }
        if (threadIdx.x == 0) st_sc(&base[1024], 1u);
    } else {
        if (threadIdx.x == 0) {
            while (ld_sc(&base[1024]) == 0u) __builtin_amdgcn_s_sleep(8);
        }
    }
    __syncthreads();
    asm volatile("" ::: "memory");
}

union ShMem {
    u32 hl[UBINS / 2];                                 // 8 KB — S1 LDS histogram (u16-packed)
    u32 wtot[4];                                       // scan wave totals
    struct { u32 wcnt[4]; u32 wbase[4]; u32 bbase; } cmp;  // compact
    struct { u64 ckeys[8]; u32 wpart[4][8]; } rank;    // rank
    struct {
        u64 Ml[2 * NMS_CHUNK * 16];                    // 32 KB double-buffered mask chunks
        u64 keepS[16];
        u32 nib[256];
        int act[TOP_K];
        u32 wsum[4];
        int nactS;
        int det[MAX_DET];
    } nms;                                             // ~37.6 KB -> 4 blocks/CU fit (155.6<=160KB)
};

// R12: launch_bounds min-waves 4/EU (16 waves/CU = 4 blocks co-resident).
// Blocks >= NPOST(512) exist ONLY to double S1's streaming TLP; they arrive
// at bar0 and exit. All post-S1 phases keep the proven 512-block structure.
__global__ void __launch_bounds__(256, 4)
mega(const float* __restrict__ cls, const float* __restrict__ regs,
     const float* __restrict__ anchors, const int* __restrict__ pH,
     const int* __restrict__ pW, int A, int C,
     char* __restrict__ ws, float* __restrict__ out)
{
    __shared__ ShMem sh;
    __shared__ u32 shcut;        // block-local cut bin
    u32*   hist   = (u32*)(ws + OFF_HIST);
    u32*   state  = (u32*)(ws + OFF_STATE);   // slot 5 (cand_cnt) at state[5*32]
    u32*   barr   = (u32*)(ws + OFF_BAR);
    u64*   cand   = (u64*)(ws + OFF_CAND);    // full sort keys (score||~a)
    u32*   rflag  = (u32*)(ws + OFF_RFLAG);
    u32*   sidx   = (u32*)(ws + OFF_SIDX);
    float* sscore = (float*)(ws + OFF_SSCORE);
    float* cbox   = (float*)(ws + OFF_CBOX);
    u64*   M      = (u64*)(ws + OFF_M);
    float* scores = (float*)(ws + OFF_SCORES);

    const int t = threadIdx.x;
    const int b = blockIdx.x;
    const int G = gridDim.x;
    const int NP = (G < 512) ? G : 512;      // post-S1 working set
    const int gid = b * 256 + t;
    const int gstride = G * 256;
    const int lane = t & 63, wv = t >> 6;

    // ---------- S1: coalesced class-max + thresholded score + u-bin hist ----------
    // hist/state/bar were zeroed by the host memset (prior dispatch).
    if (C == 80) {
        for (int i = t; i < UBINS / 2; i += 256) sh.hl[i] = 0;
        __syncthreads();
        int sub = t & 3;           // which 20-float quarter of the 80 classes
        int la  = t >> 2;          // local anchor 0..63
        int nstrips = (A + 63) >> 6;
        int per = (nstrips + G - 1) / G;
        for (int s = 0; s < per; s++) {
            int a = (b * per + s) * 64 + la;
            float m = -1e30f;
            if (a < A) {
                const float* p = cls + (size_t)a * 80 + sub * 4;
                #pragma unroll
                for (int k2 = 0; k2 < 5; k2++) {
                    float4 v = *(const float4*)(p + k2 * 16);
                    m = fmaxf(m, fmaxf(fmaxf(v.x, v.y), fmaxf(v.z, v.w)));
                }
            }
            m = fmaxf(m, __shfl_xor(m, 1, 64));
            m = fmaxf(m, __shfl_xor(m, 2, 64));
            if (sub == 0 && a < A) {
                float s0 = (m > SCORE_THRESH) ? m : -1.0f;
                st_sc(&scores[a], s0);                  // sc1: visible at MALL
                u32 d = ubin(s0);
                atomicAdd(&sh.hl[d >> 1], (d & 1) ? 0x10000u : 1u);
            }
        }
        __syncthreads();
        u32* rep = hist + (size_t)(b & (NREP - 1)) * UBINS;
        for (int i = t; i < UBINS / 2; i += 256) {
            u32 v = sh.hl[i];
            if (v & 0xFFFFu) atomicAdd(&rep[2 * i],     v & 0xFFFFu);   // memory-side RMW
            if (v >> 16)     atomicAdd(&rep[2 * i + 1], v >> 16);
        }
    } else {
        u32* rep = hist + (size_t)(b & (NREP - 1)) * UBINS;
        for (int a = gid; a < A; a += gstride) {
            const float* p = cls + (size_t)a * C;
            float m = -1e30f;
            for (int c = 0; c < C; c++) m = fmaxf(m, p[c]);
            float s0 = (m > SCORE_THRESH) ? m : -1.0f;
            st_sc(&scores[a], s0);
            atomicAdd(&rep[ubin(s0)], 1u);
        }
    }
    {
        bool post = (b < NP);
        gbar(barr, 0, b, G, post);           // sweep ALL G arrivals
        if (!post) return;                   // S1-only boost blocks exit here
    }

    const int gid2 = b * 256 + t;
    const int gstride2 = NP * 256;

    // ---------- S2: single scan, REDUNDANT in every post block ----------
    {
        if (t == 0) shcut = UBINS - 1;       // default: include all (A < TOP_K case)
        u32 cnt[16];
        #pragma unroll
        for (int i = 0; i < 16; i++) cnt[i] = 0;
        const uint4* hp = (const uint4*)hist;
        #pragma unroll
        for (int r = 0; r < NREP; r++) {
            #pragma unroll
            for (int i = 0; i < 4; i++) {
                uint4 v = hp[r * (UBINS / 4) + t * 4 + i];
                cnt[4*i]   += v.x; cnt[4*i+1] += v.y;
                cnt[4*i+2] += v.z; cnt[4*i+3] += v.w;
            }
        }
        u32 s = 0;
        #pragma unroll
        for (int i = 0; i < 16; i++) s += cnt[i];
        u32 x = s;   // inclusive prefix within wave (ascending lanes)
        for (int off = 1; off < 64; off <<= 1) {
            u32 v = (u32)__shfl_up((int)x, off, 64);
            if (lane >= off) x += v;
        }
        if (lane == 63) sh.wtot[wv] = x;
        __syncthreads();
        u32 below = x - s;
        for (int w = 0; w < wv; w++) below += sh.wtot[w];
        if (below < TOP_K && below + s >= TOP_K) {
            u32 cum = below;
            for (int i = 0; i < 16; i++) {
                cum += cnt[i];
                if (cum >= TOP_K) { shcut = (u32)(t * 16 + i); break; }
            }
        }
        __syncthreads();
    }
    const u32 cutbin = shcut;

    // ---------- S3: compact (ubin <= cutbin) -> 64-bit KEYS, one atomic/block ----------
    {
        int nr = (A + gstride2 - 1) / gstride2;
        u32 mycnt = 0;
        for (int r = 0; r < nr; r++) {
            int a = gid2 + r * gstride2;
            mycnt += ((a < A) && (ubin(scores[a]) <= cutbin)) ? 1u : 0u;
        }
        u32 wc = mycnt;
        wc += (u32)__shfl_xor((int)wc, 1, 64);
        wc += (u32)__shfl_xor((int)wc, 2, 64);
        wc += (u32)__shfl_xor((int)wc, 4, 64);
        wc += (u32)__shfl_xor((int)wc, 8, 64);
        wc += (u32)__shfl_xor((int)wc, 16, 64);
        wc += (u32)__shfl_xor((int)wc, 32, 64);
        if (lane == 0) sh.cmp.wcnt[wv] = wc;
        __syncthreads();
        if (t == 0) {
            u32 s = 0;
            #pragma unroll
            for (int w = 0; w < 4; w++) { sh.cmp.wbase[w] = s; s += sh.cmp.wcnt[w]; }
            sh.cmp.bbase = s ? atomicAdd(&state[5 * 32], s) : 0u;
        }
        __syncthreads();
        u32 off = sh.cmp.bbase + sh.cmp.wbase[wv];
        for (int r = 0; r < nr; r++) {
            int a = gid2 + r * gstride2;
            float s0 = (a < A) ? scores[a] : 0.0f;
            bool pass = (a < A) && (ubin(s0) <= cutbin);
            u64 mask = __ballot(pass ? 1 : 0);
            if (pass) {
                u32 pos = off + (u32)__popcll(mask & ((1ull << lane) - 1ull));
                if (pos < CAND_CAP) {
                    u64 key = ((u64)order_f32(s0) << 32) | (u64)(0xFFFFFFFFu - (u32)a);
                    st_sc(&cand[pos], key);
                }
            }
            off += (u32)__popcll(mask);
        }
    }
    gbar(barr, 1, b, NP, b < CAND_CAP / 8);  // rank participants wait

    // ---------- S4: exact parallel rank + decode ----------
    if (b < CAND_CAP / 8) {
        int n = (int)state[5 * 32]; if (n > CAND_CAP) n = CAND_CAP;   // first-touch
        u64 kj[8];                           // this thread's j-strip of keys
        #pragma unroll
        for (int q = 0; q < 8; q++) {
            int j = t * 8 + q;
            kj[q] = (j < n) ? cand[j] : 0ull;    // contiguous; pads sort last
        }
        for (int bb = b; bb < CAND_CAP / 8; bb += NP) {
            if (t < 8) {
                int c = bb * 8 + t;
                sh.rank.ckeys[t] = (c < n) ? cand[c] : 0ull;
            }
            __syncthreads();
            u64 ck[8];
            #pragma unroll
            for (int q = 0; q < 8; q++) ck[q] = sh.rank.ckeys[q];
            u32 cnt8[8] = {0,0,0,0,0,0,0,0};
            #pragma unroll
            for (int q = 0; q < 8; q++) {
                u64 kq = kj[q];
                #pragma unroll
                for (int q2 = 0; q2 < 8; q2++) cnt8[q2] += (kq > ck[q2]) ? 1u : 0u;
            }
            #pragma unroll
            for (int q2 = 0; q2 < 8; q2++) {
                u32 x = cnt8[q2];
                x += (u32)__shfl_xor((int)x, 1, 64);
                x += (u32)__shfl_xor((int)x, 2, 64);
                x += (u32)__shfl_xor((int)x, 4, 64);
                x += (u32)__shfl_xor((int)x, 8, 64);
                x += (u32)__shfl_xor((int)x, 16, 64);
                x += (u32)__shfl_xor((int)x, 32, 64);
                if (lane == 0) sh.rank.wpart[wv][q2] = x;
            }
            __syncthreads();
            if (t < 8) {
                int c = bb * 8 + t;
                if (c < n) {
                    u32 rank = sh.rank.wpart[0][t] + sh.rank.wpart[1][t]
                             + sh.rank.wpart[2][t] + sh.rank.wpart[3][t];
                    if (rank < TOP_K) {
                        u64 kk = ck[t];
                        u32 a = 0xFFFFFFFFu - (u32)(kk & 0xFFFFFFFFull);
                        u32 hi = (u32)(kk >> 32);
                        u32 bits = (hi & 0x80000000u) ? (hi & 0x7FFFFFFFu) : ~hi;
                        st_sc(&sidx[rank], a);
                        st_sc(&sscore[rank], __uint_as_float(bits));
                        float4 an = *(const float4*)(anchors + (size_t)a * 4);
                        float4 rg = *(const float4*)(regs + (size_t)a * 4);
                        float aw = an.z - an.x, ah = an.w - an.y;
                        float acx = an.x + 0.5f * aw, acy = an.y + 0.5f * ah;
                        float pcx = acx + (rg.x * 0.1f) * aw;
                        float pcy = acy + (rg.y * 0.1f) * ah;
                        float pw = expf(rg.z * 0.2f) * aw;
                        float ph = expf(rg.w * 0.2f) * ah;
                        float W = (float)(*pW), H = (float)(*pH);
                        st_sc(&cbox[rank * 4 + 0], fminf(fmaxf(pcx - 0.5f * pw, 0.0f), W));
                        st_sc(&cbox[rank * 4 + 1], fminf(fmaxf(pcy - 0.5f * ph, 0.0f), H));
                        st_sc(&cbox[rank * 4 + 2], fminf(fmaxf(pcx + 0.5f * pw, 0.0f), W));
                        st_sc(&cbox[rank * 4 + 3], fminf(fmaxf(pcy + 0.5f * ph, 0.0f), H));
                    }
                }
            }
            __syncthreads();
        }
    }
    gbar(barr, 2, b, NP, b == 0 || (b - 1) * 4 < TOP_K);   // IoU + block 0 wait

    // ---------- S5: IoU bit-matrix on blocks 1..250 ∥ keep-init on block 0 ----------
    if (b >= 1) {
        const float4* B4 = (const float4*)cbox;   // first-touch -> MALL, then cached
        for (int i = (b - 1) * 4 + wv; i < TOP_K; i += (NP - 1) * 4) {
            float4 bi = B4[i];
            float ai = fmaxf(bi.z - bi.x, 0.0f) * fmaxf(bi.w - bi.y, 0.0f);
            u64 any = 0ull;
            int w0 = i >> 6;                      // words < w0: all j < i -> zero
            if (lane == 0)
                for (int w = 0; w < w0; w++) st_sc(&M[(size_t)i * 16 + w], 0ull);
            for (int w = w0; w < 16; w++) {
                int j = w * 64 + lane;
                bool sup = false;
                if (j < TOP_K && j > i) {
                    float4 bj = B4[j];
                    float aj = fmaxf(bj.z - bj.x, 0.0f) * fmaxf(bj.w - bj.y, 0.0f);
                    float xx1 = fmaxf(bi.x, bj.x), yy1 = fmaxf(bi.y, bj.y);
                    float xx2 = fminf(bi.z, bj.z), yy2 = fminf(bi.w, bj.w);
                    float inter = fmaxf(xx2 - xx1, 0.0f) * fmaxf(yy2 - yy1, 0.0f);
                    float iou = inter / (ai + aj - inter + 1e-8f);
                    sup = iou > IOU_THRESH;
                }
                u64 mask = __ballot(sup ? 1 : 0);
                if (lane == 0) { st_sc(&M[(size_t)i * 16 + w], mask); any |= mask; }
            }
            if (lane == 0) st_sc(&rflag[i], (any != 0ull) ? 1u : 0u);
        }
    } else {
        // Block 0 (excluded from IoU) pre-builds the keep bitmask from sscore
        // (ready since bar2) -> shortens the serial NMS tail after bar3.
        u32 nb = 0;
        int j0 = 4 * t;
        #pragma unroll
        for (int q = 0; q < 4; q++) {
            int j = j0 + q;
            if (j < TOP_K && sscore[j] > SCORE_THRESH) nb |= (1u << q);
        }
        sh.nms.nib[t] = nb;
        __syncthreads();
        if (t < 16) {
            u64 w = 0;
            for (int m2 = 0; m2 < 16; m2++)
                w |= ((u64)sh.nms.nib[t * 16 + m2]) << (4 * m2);
            sh.nms.keepS[t] = w;
        }
    }
    gbar(barr, 3, b, NP, b == 0);            // only block 0 (S6) consumes

    // ---------- S6: greedy NMS over active rows + finalize (block 0) ----------
    if (b == 0) {
        u32 flags = 0; int cnt = 0;
        {
            int r0 = 4 * t;
            #pragma unroll
            for (int q = 0; q < 4; q++) {
                int r = r0 + q;
                if (r < TOP_K && rflag[r]) { flags |= (1u << q); cnt++; }
            }
        }
        int x = cnt;
        for (int off = 1; off < 64; off <<= 1) {
            int v = __shfl_up(x, off, 64);
            if (lane >= off) x += v;
        }
        if (lane == 63) sh.nms.wsum[wv] = (u32)x;
        __syncthreads();
        int base = 0;
        for (int w = 0; w < wv; w++) base += (int)sh.nms.wsum[w];
        int pos = base + x - cnt;
        {
            int r0 = 4 * t;
            #pragma unroll
            for (int q = 0; q < 4; q++)
                if (flags & (1u << q)) sh.nms.act[pos++] = r0 + q;
        }
        if (t == 0) {
            int na = 0;
            for (int w = 0; w < 4; w++) na += (int)sh.nms.wsum[w];
            sh.nms.nactS = na;
        }
        __syncthreads();
        int nact = sh.nms.nactS;
        int nchunks = (nact + NMS_CHUNK - 1) / NMS_CHUNK;

        // Double-buffered chunked greedy with register-prefetched mask rows.
        if (nchunks > 0) {
            int cn0 = (nact < NMS_CHUNK) ? nact : NMS_CHUNK;
            for (int i = t; i < cn0 * 16; i += 256) {
                int row = sh.nms.act[i >> 4];
                sh.nms.Ml[i] = M[(size_t)row * 16 + (i & 15)];
            }
        }
        __syncthreads();
        u64 kp = (wv == 0 && lane < 16) ? sh.nms.keepS[lane] : 0ull;
        for (int ci = 0; ci < nchunks; ci++) {
            int c0 = ci * NMS_CHUNK;
            int cn = (nact - c0 < NMS_CHUNK) ? (nact - c0) : NMS_CHUNK;
            int cur = (ci & 1) * (NMS_CHUNK * 16);
            if (ci + 1 < nchunks && t >= 64) {
                int c0n = c0 + NMS_CHUNK;
                int cnn = (nact - c0n < NMS_CHUNK) ? (nact - c0n) : NMS_CHUNK;
                int nxt = ((ci + 1) & 1) * (NMS_CHUNK * 16);
                for (int i = t - 64; i < cnn * 16; i += 192) {
                    int row = sh.nms.act[c0n + (i >> 4)];
                    sh.nms.Ml[nxt + i] = M[(size_t)row * 16 + (i & 15)];
                }
            }
            if (wv == 0) {
                u64 mreg = (lane < 16 && cn > 0) ? sh.nms.Ml[cur + lane] : 0ull;
                for (int k = 0; k < cn; k++) {
                    u64 mnx = (lane < 16 && k + 1 < cn)
                            ? sh.nms.Ml[cur + (k + 1) * 16 + lane] : 0ull;
                    int i = sh.nms.act[c0 + k];
                    u64 kw = __shfl(kp, i >> 6, 64);
                    if ((kw >> (i & 63)) & 1ull) kp &= ~mreg;
                    mreg = mnx;
                }
            }
            __syncthreads();
        }
        if (wv == 0 && lane < 16) sh.nms.keepS[lane] = kp;
        __syncthreads();

        if (t == 0) {
            int cnt2 = 0;
            for (int w = 0; w < 16 && cnt2 < MAX_DET; w++) {
                u64 kw = sh.nms.keepS[w];
                while (kw && cnt2 < MAX_DET) {
                    int bbit = __ffsll((unsigned long long)kw) - 1;
                    sh.nms.det[cnt2++] = w * 64 + bbit;
                    kw &= kw - 1;
                }
            }
            for (; cnt2 < MAX_DET; cnt2++) sh.nms.det[cnt2] = -1;
        }
        __syncthreads();
        if (t < MAX_DET) {
            int i = sh.nms.det[t];
            if (i >= 0) {
                u32 a = sidx[i];
                const float* p = cls + (size_t)a * C;
                float best = -1e30f; int bc = 0;
                if (C == 80) {
                    #pragma unroll
                    for (int c4 = 0; c4 < 20; c4++) {
                        float4 v = *(const float4*)(p + c4 * 4);
                        if (v.x > best) { best = v.x; bc = c4 * 4; }
                        if (v.y > best) { best = v.y; bc = c4 * 4 + 1; }
                        if (v.z > best) { best = v.z; bc = c4 * 4 + 2; }
                        if (v.w > best) { best = v.w; bc = c4 * 4 + 3; }
                    }
                } else {
                    best = p[0]; bc = 0;
                    for (int c = 1; c < C; c++) {
                        float v = p[c];
                        if (v > best) { best = v; bc = c; }
                    }
                }
                out[t] = best;
                out[MAX_DET + t] = (float)bc;
                out[2 * MAX_DET + t * 4 + 0] = cbox[i * 4 + 0];
                out[2 * MAX_DET + t * 4 + 1] = cbox[i * 4 + 1];
                out[2 * MAX_DET + t * 4 + 2] = cbox[i * 4 + 2];
                out[2 * MAX_DET + t * 4 + 3] = cbox[i * 4 + 3];
            } else {
                out[t] = 0.0f;
                out[MAX_DET + t] = -1.0f;
                out[2 * MAX_DET + t * 4 + 0] = 0.0f;
                out[2 * MAX_DET + t * 4 + 1] = 0.0f;
                out[2 * MAX_DET + t * 4 + 2] = 0.0f;
                out[2 * MAX_DET + t * 4 + 3] = 0.0f;
            }
        }
    }
}

extern "C" void kernel_launch(void* const* d_in, const int* in_sizes, int n_in,
                              void* d_out, int out_size, void* d_ws, size_t ws_size,
                              hipStream_t stream) {
    (void)n_in; (void)out_size; (void)ws_size;
    const float* cls     = (const float*)d_in[0];
    const float* regs    = (const float*)d_in[1];
    const float* anchors = (const float*)d_in[2];
    const int*   pH      = (const int*)d_in[3];
    const int*   pW      = (const int*)d_in[4];
    int A = in_sizes[1] / 4;
    int C = in_sizes[0] / A;

    // R12: grid = (blocks/CU measured by the runtime, capped at 4) x nCU.
    // 4 blocks/CU fit by LDS (4x38.9KB = 155.6 <= 160KB); the occupancy query
    // guards against rounding surprises (fallback = the proven 2/CU config).
    // Co-residency of ALL launched blocks is required for bar0 (deadlock
    // safety), hence G = perCU * nCU exactly.
    static int G = 0;
    if (G <= 0) {
        int dev = 0, nCU = 0, occ = 0;
        hipGetDevice(&dev);
        hipDeviceGetAttribute(&nCU, hipDeviceAttributeMultiprocessorCount, dev);
        if (nCU <= 0) nCU = 256;
        hipOccupancyMaxActiveBlocksPerMultiprocessor(&occ, mega, 256, 0);
        if (occ < 1) occ = 1;
        if (occ > 4) occ = 4;
        G = occ * nCU;
        if (G > 1024) G = 1024;
        if (G < 8) G = 8;
    }

    char* ws = (char*)d_ws;
    // Zero hist + state + barrier flags in one memset; the fill dispatch's
    // completion makes the zeros coherence-point visible.
    hipMemsetAsync(ws, 0, MEMSET_LEN, stream);
    mega<<<dim3(G), dim3(256), 0, stream>>>(cls, regs, anchors, pH, pW, A, C,
                                            ws, (float*)d_out);
}

// Round 13
// 149.370 us; speedup vs baseline: 1.0276x; 1.0276x over previous
//
#include <hip/hip_runtime.h>
#include <stdint.h>

#define SCORE_THRESH 0.05f
#define IOU_THRESH 0.5f
#define TOP_K 1000
#define MAX_DET 100

#define UBINS 4096             // 12-bit nonuniform bins on u=1-s (exp+5 mantissa)
#define NREP 4                 // replicated histograms (flush-contention relief)
#define CAND_CAP 2048
#define NMS_CHUNK 128          // rows per NMS staging chunk (dbuf: 2x128x16 u64 = 32KB)

typedef unsigned int u32;
typedef unsigned long long u64;

// ---- ws layout (bytes) ----
// [hist][state][bar] is one contiguous host-memset region.
#define OFF_HIST     0          // u32[NREP*4096] = 65536
#define OFF_STATE    65536      // 1024 -> 66560 (slot5 = cand_cnt at [5*32])
#define OFF_BAR      66560      // 4 barriers x 4096B -> 82944
#define MEMSET_LEN   82944
#define OFF_CAND     82944      // u64[2048] = 16384 -> 99328 (full keys, no rank gather)
#define OFF_RFLAG    99328      // u32[1000] -> 103328
#define OFF_SIDX     103328     // u32[1000] -> 107328
#define OFF_SSCORE   107328     // float[1000] -> 111328
#define OFF_CBOX     111328     // float[4000] -> 127328 (16B aligned)
#define OFF_M        127328     // u64[1000*16] = 128000 -> 255328 (8B aligned)
#define OFF_SCORES   255328     // float[A]

#define BAR_STRIDE_U32 1024     // per barrier: flags[0..511], go word at [512]

__device__ __forceinline__ u32 order_f32(float f) {
    u32 b = __float_as_uint(f);
    return (b & 0x80000000u) ? ~b : (b | 0x80000000u);
}

// Distribution-matched 12-bit bin, ASCENDING in u=1-s (descending score).
// Exact for s in [0.5,1] (Sterbenz), monotone everywhere; exponent bits give
// log-scale tail resolution so ONE histogram pass resolves the top-1000 cut
// (cut bin holds ~31 anchors). Sentinel s0=-1 -> u=2.0 -> clamped 4095.
__device__ __forceinline__ u32 ubin(float s0) {
    float u = 1.0f - s0;
    u32 bin = __float_as_uint(u) >> 18;      // sign(0)+exp(8)+mantissa(5)
    return bin > (UBINS - 1) ? (UBINS - 1) : bin;
}

// MALL-direct (sc1) accessors: relaxed agent-scope atomics carry no fence ->
// no buffer_wbl2/buffer_inv ever. Stores write through to the coherence
// point; loads bypass stale caches.
__device__ __forceinline__ void st_sc(u32* p, u32 v)   { __hip_atomic_store(p, v, __ATOMIC_RELAXED, __HIP_MEMORY_SCOPE_AGENT); }
__device__ __forceinline__ void st_sc(float* p, float v){ __hip_atomic_store(p, v, __ATOMIC_RELAXED, __HIP_MEMORY_SCOPE_AGENT); }
__device__ __forceinline__ void st_sc(u64* p, u64 v)   { __hip_atomic_store(p, v, __ATOMIC_RELAXED, __HIP_MEMORY_SCOPE_AGENT); }
__device__ __forceinline__ u32  ld_sc(u32* p)          { return __hip_atomic_load(p, __ATOMIC_RELAXED, __HIP_MEMORY_SCOPE_AGENT); }

// Device-wide barrier v5 (R10/R11-proven best): parallel flag arrival (1 sc1
// store per block, zero RMWs) + SINGLE sweeper (block 0, 2 loads/thread) +
// one-line go-word poll for everyone else. Ledger: R1 inv-storm 620us; R2
// tag-walks 271us; R3/R7 counter-tree 98us; R8 all-blocks-sweep 124us;
// v5 -> 68us. R12: wider grid for S1 = null (S1 already BW-saturated).
// Correctness: __syncthreads + vmcnt(0) put this block's sc1 data stores at
// the coherence point before its flag store; readers first-touch data lines
// only after the producing barrier (layout discipline). Flags monotone 0->1,
// host-zeroed; non-waiting blocks race ahead safely.
__device__ __forceinline__ void gbar(u32* barr, int k, int b, int G, bool dowait) {
    __syncthreads();
    u32* base = barr + (size_t)k * BAR_STRIDE_U32;
    if (threadIdx.x == 0) {
        asm volatile("s_waitcnt vmcnt(0)" ::: "memory");
        st_sc(&base[b], 1u);
    }
    if (!dowait) return;
    if (b == 0) {
        for (;;) {
            int my = 1;
            for (int i = (int)threadIdx.x; i < G; i += 256) my &= (int)ld_sc(&base[i]);
            if (__syncthreads_and(my)) break;
        }
        if (threadIdx.x == 0) st_sc(&base[512], 1u);
    } else {
        if (threadIdx.x == 0) {
            while (ld_sc(&base[512]) == 0u) __builtin_amdgcn_s_sleep(8);
        }
    }
    __syncthreads();
    asm volatile("" ::: "memory");
}

union ShMem {
    u32 hl[UBINS / 2];                                 // 8 KB — S1 LDS histogram (u16-packed)
    u32 wtot[4];                                       // scan wave totals
    struct { u32 wcnt[4]; u32 wbase[4]; u32 bbase; } cmp;  // compact
    struct { u64 ckeys[8]; u32 wpart[4][8]; } rank;    // rank
    struct {
        u64 Ml[2 * NMS_CHUNK * 16];                    // 32 KB double-buffered mask chunks
        u64 keepS[16];
        u32 nib[256];
        int act[TOP_K];
        u32 wsum[4];
        int nactS;
        int det[MAX_DET];
    } nms;                                             // ~37.6 KB total (proven footprint)
};

__global__ void __launch_bounds__(256, 2)
mega(const float* __restrict__ cls, const float* __restrict__ regs,
     const float* __restrict__ anchors, const int* __restrict__ pH,
     const int* __restrict__ pW, int A, int C,
     char* __restrict__ ws, float* __restrict__ out)
{
    __shared__ ShMem sh;
    __shared__ u32 shcut;        // block-local cut bin
    u32*   hist   = (u32*)(ws + OFF_HIST);
    u32*   state  = (u32*)(ws + OFF_STATE);   // slot 5 (cand_cnt) at state[5*32]
    u32*   barr   = (u32*)(ws + OFF_BAR);
    u64*   cand   = (u64*)(ws + OFF_CAND);    // full sort keys (score||~a)
    u32*   rflag  = (u32*)(ws + OFF_RFLAG);
    u32*   sidx   = (u32*)(ws + OFF_SIDX);
    float* sscore = (float*)(ws + OFF_SSCORE);
    float* cbox   = (float*)(ws + OFF_CBOX);
    u64*   M      = (u64*)(ws + OFF_M);
    float* scores = (float*)(ws + OFF_SCORES);

    const int t = threadIdx.x;
    const int b = blockIdx.x;
    const int G = gridDim.x;
    const int gid = b * 256 + t;
    const int gstride = G * 256;
    const int lane = t & 63, wv = t >> 6;

    // ---------- S1: coalesced class-max + thresholded score + u-bin hist ----------
    // hist/state/bar were zeroed by the host memset (prior dispatch).
    if (C == 80) {
        for (int i = t; i < UBINS / 2; i += 256) sh.hl[i] = 0;
        __syncthreads();
        int sub = t & 3;           // which 20-float quarter of the 80 classes
        int la  = t >> 2;          // local anchor 0..63
        int nstrips = (A + 63) >> 6;
        int per = (nstrips + G - 1) / G;
        for (int s = 0; s < per; s++) {
            int a = (b * per + s) * 64 + la;
            float m = -1e30f;
            if (a < A) {
                const float* p = cls + (size_t)a * 80 + sub * 4;
                #pragma unroll
                for (int k2 = 0; k2 < 5; k2++) {
                    float4 v = *(const float4*)(p + k2 * 16);
                    m = fmaxf(m, fmaxf(fmaxf(v.x, v.y), fmaxf(v.z, v.w)));
                }
            }
            m = fmaxf(m, __shfl_xor(m, 1, 64));
            m = fmaxf(m, __shfl_xor(m, 2, 64));
            if (sub == 0 && a < A) {
                float s0 = (m > SCORE_THRESH) ? m : -1.0f;
                st_sc(&scores[a], s0);                  // sc1: visible at MALL
                u32 d = ubin(s0);
                atomicAdd(&sh.hl[d >> 1], (d & 1) ? 0x10000u : 1u);
            }
        }
        __syncthreads();
        u32* rep = hist + (size_t)(b & (NREP - 1)) * UBINS;
        for (int i = t; i < UBINS / 2; i += 256) {
            u32 v = sh.hl[i];
            if (v & 0xFFFFu) atomicAdd(&rep[2 * i],     v & 0xFFFFu);   // memory-side RMW
            if (v >> 16)     atomicAdd(&rep[2 * i + 1], v >> 16);
        }
    } else {
        u32* rep = hist + (size_t)(b & (NREP - 1)) * UBINS;
        for (int a = gid; a < A; a += gstride) {
            const float* p = cls + (size_t)a * C;
            float m = -1e30f;
            for (int c = 0; c < C; c++) m = fmaxf(m, p[c]);
            float s0 = (m > SCORE_THRESH) ? m : -1.0f;
            st_sc(&scores[a], s0);
            atomicAdd(&rep[ubin(s0)], 1u);
        }
    }
    gbar(barr, 0, b, G, true);               // hist complete; everyone scans it

    // ---------- S2: single scan, REDUNDANT in every block ----------
    {
        if (t == 0) shcut = UBINS - 1;       // default: include all (A < TOP_K case)
        u32 cnt[16];
        #pragma unroll
        for (int i = 0; i < 16; i++) cnt[i] = 0;
        const uint4* hp = (const uint4*)hist;
        #pragma unroll
        for (int r = 0; r < NREP; r++) {
            #pragma unroll
            for (int i = 0; i < 4; i++) {
                uint4 v = hp[r * (UBINS / 4) + t * 4 + i];
                cnt[4*i]   += v.x; cnt[4*i+1] += v.y;
                cnt[4*i+2] += v.z; cnt[4*i+3] += v.w;
            }
        }
        u32 s = 0;
        #pragma unroll
        for (int i = 0; i < 16; i++) s += cnt[i];
        u32 x = s;   // inclusive prefix within wave (ascending lanes)
        for (int off = 1; off < 64; off <<= 1) {
            u32 v = (u32)__shfl_up((int)x, off, 64);
            if (lane >= off) x += v;
        }
        if (lane == 63) sh.wtot[wv] = x;
        __syncthreads();
        u32 below = x - s;
        for (int w = 0; w < wv; w++) below += sh.wtot[w];
        if (below < TOP_K && below + s >= TOP_K) {
            u32 cum = below;
            for (int i = 0; i < 16; i++) {
                cum += cnt[i];
                if (cum >= TOP_K) { shcut = (u32)(t * 16 + i); break; }
            }
        }
        __syncthreads();
    }
    const u32 cutbin = shcut;

    // ---------- S3: compact (ubin <= cutbin) -> 64-bit KEYS, one atomic/block ----------
    // cand stores (order(score)||~a). Rank then needs ONE contiguous 16KB
    // load instead of ~1030 scattered score-gathers per participating block.
    {
        int nr = (A + gstride - 1) / gstride;
        u32 mycnt = 0;
        for (int r = 0; r < nr; r++) {
            int a = gid + r * gstride;
            mycnt += ((a < A) && (ubin(scores[a]) <= cutbin)) ? 1u : 0u;
        }
        u32 wc = mycnt;
        wc += (u32)__shfl_xor((int)wc, 1, 64);
        wc += (u32)__shfl_xor((int)wc, 2, 64);
        wc += (u32)__shfl_xor((int)wc, 4, 64);
        wc += (u32)__shfl_xor((int)wc, 8, 64);
        wc += (u32)__shfl_xor((int)wc, 16, 64);
        wc += (u32)__shfl_xor((int)wc, 32, 64);
        if (lane == 0) sh.cmp.wcnt[wv] = wc;
        __syncthreads();
        if (t == 0) {
            u32 s = 0;
            #pragma unroll
            for (int w = 0; w < 4; w++) { sh.cmp.wbase[w] = s; s += sh.cmp.wcnt[w]; }
            sh.cmp.bbase = s ? atomicAdd(&state[5 * 32], s) : 0u;
        }
        __syncthreads();
        u32 off = sh.cmp.bbase + sh.cmp.wbase[wv];
        for (int r = 0; r < nr; r++) {
            int a = gid + r * gstride;
            float s0 = (a < A) ? scores[a] : 0.0f;
            bool pass = (a < A) && (ubin(s0) <= cutbin);
            u64 mask = __ballot(pass ? 1 : 0);
            if (pass) {
                u32 pos = off + (u32)__popcll(mask & ((1ull << lane) - 1ull));
                if (pos < CAND_CAP) {
                    u64 key = ((u64)order_f32(s0) << 32) | (u64)(0xFFFFFFFFu - (u32)a);
                    st_sc(&cand[pos], key);
                }
            }
            off += (u32)__popcll(mask);
        }
    }
    gbar(barr, 1, b, G, b < CAND_CAP / 8);   // rank participants wait

    // ---------- S4: exact parallel rank + decode ----------
    if (b < CAND_CAP / 8) {
        int n = (int)state[5 * 32]; if (n > CAND_CAP) n = CAND_CAP;   // first-touch
        u64 kj[8];                           // this thread's j-strip of keys
        #pragma unroll
        for (int q = 0; q < 8; q++) {
            int j = t * 8 + q;
            kj[q] = (j < n) ? cand[j] : 0ull;    // contiguous; pads sort last
        }
        for (int bb = b; bb < CAND_CAP / 8; bb += G) {
            if (t < 8) {
                int c = bb * 8 + t;
                sh.rank.ckeys[t] = (c < n) ? cand[c] : 0ull;
            }
            __syncthreads();
            u64 ck[8];
            #pragma unroll
            for (int q = 0; q < 8; q++) ck[q] = sh.rank.ckeys[q];
            u32 cnt8[8] = {0,0,0,0,0,0,0,0};
            #pragma unroll
            for (int q = 0; q < 8; q++) {
                u64 kq = kj[q];
                #pragma unroll
                for (int q2 = 0; q2 < 8; q2++) cnt8[q2] += (kq > ck[q2]) ? 1u : 0u;
            }
            #pragma unroll
            for (int q2 = 0; q2 < 8; q2++) {
                u32 x = cnt8[q2];
                x += (u32)__shfl_xor((int)x, 1, 64);
                x += (u32)__shfl_xor((int)x, 2, 64);
                x += (u32)__shfl_xor((int)x, 4, 64);
                x += (u32)__shfl_xor((int)x, 8, 64);
                x += (u32)__shfl_xor((int)x, 16, 64);
                x += (u32)__shfl_xor((int)x, 32, 64);
                if (lane == 0) sh.rank.wpart[wv][q2] = x;
            }
            __syncthreads();
            if (t < 8) {
                int c = bb * 8 + t;
                if (c < n) {
                    u32 rank = sh.rank.wpart[0][t] + sh.rank.wpart[1][t]
                             + sh.rank.wpart[2][t] + sh.rank.wpart[3][t];
                    if (rank < TOP_K) {
                        u64 kk = ck[t];
                        u32 a = 0xFFFFFFFFu - (u32)(kk & 0xFFFFFFFFull);
                        u32 hi = (u32)(kk >> 32);
                        u32 bits = (hi & 0x80000000u) ? (hi & 0x7FFFFFFFu) : ~hi;
                        st_sc(&sidx[rank], a);
                        st_sc(&sscore[rank], __uint_as_float(bits));
                        float4 an = *(const float4*)(anchors + (size_t)a * 4);
                        float4 rg = *(const float4*)(regs + (size_t)a * 4);
                        float aw = an.z - an.x, ah = an.w - an.y;
                        float acx = an.x + 0.5f * aw, acy = an.y + 0.5f * ah;
                        float pcx = acx + (rg.x * 0.1f) * aw;
                        float pcy = acy + (rg.y * 0.1f) * ah;
                        float pw = expf(rg.z * 0.2f) * aw;
                        float ph = expf(rg.w * 0.2f) * ah;
                        float W = (float)(*pW), H = (float)(*pH);
                        st_sc(&cbox[rank * 4 + 0], fminf(fmaxf(pcx - 0.5f * pw, 0.0f), W));
                        st_sc(&cbox[rank * 4 + 1], fminf(fmaxf(pcy - 0.5f * ph, 0.0f), H));
                        st_sc(&cbox[rank * 4 + 2], fminf(fmaxf(pcx + 0.5f * pw, 0.0f), W));
                        st_sc(&cbox[rank * 4 + 3], fminf(fmaxf(pcy + 0.5f * ph, 0.0f), H));
                    }
                }
            }
            __syncthreads();
        }
    }
    gbar(barr, 2, b, G, b == 0 || (b - 1) * 4 < TOP_K);   // IoU + block 0 wait

    // ---------- S5: IoU bit-matrix on blocks 1..250 ∥ keep-init on block 0 ----------
    if (b >= 1) {
        const float4* B4 = (const float4*)cbox;   // first-touch -> MALL, then cached
        for (int i = (b - 1) * 4 + wv; i < TOP_K; i += (G - 1) * 4) {
            float4 bi = B4[i];
            float ai = fmaxf(bi.z - bi.x, 0.0f) * fmaxf(bi.w - bi.y, 0.0f);
            u64 any = 0ull;
            int w0 = i >> 6;                      // words < w0: all j < i -> zero
            if (lane == 0)
                for (int w = 0; w < w0; w++) st_sc(&M[(size_t)i * 16 + w], 0ull);
            for (int w = w0; w < 16; w++) {
                int j = w * 64 + lane;
                bool sup = false;
                if (j < TOP_K && j > i) {
                    float4 bj = B4[j];
                    float aj = fmaxf(bj.z - bj.x, 0.0f) * fmaxf(bj.w - bj.y, 0.0f);
                    float xx1 = fmaxf(bi.x, bj.x), yy1 = fmaxf(bi.y, bj.y);
                    float xx2 = fminf(bi.z, bj.z), yy2 = fminf(bi.w, bj.w);
                    float inter = fmaxf(xx2 - xx1, 0.0f) * fmaxf(yy2 - yy1, 0.0f);
                    float iou = inter / (ai + aj - inter + 1e-8f);
                    sup = iou > IOU_THRESH;
                }
                u64 mask = __ballot(sup ? 1 : 0);
                if (lane == 0) { st_sc(&M[(size_t)i * 16 + w], mask); any |= mask; }
            }
            if (lane == 0) st_sc(&rflag[i], (any != 0ull) ? 1u : 0u);
        }
    } else {
        // Block 0 (excluded from IoU) pre-builds the keep bitmask from sscore
        // (ready since bar2) -> shortens the serial NMS tail after bar3.
        u32 nb = 0;
        int j0 = 4 * t;
        #pragma unroll
        for (int q = 0; q < 4; q++) {
            int j = j0 + q;
            if (j < TOP_K && sscore[j] > SCORE_THRESH) nb |= (1u << q);
        }
        sh.nms.nib[t] = nb;
        __syncthreads();
        if (t < 16) {
            u64 w = 0;
            for (int m2 = 0; m2 < 16; m2++)
                w |= ((u64)sh.nms.nib[t * 16 + m2]) << (4 * m2);
            sh.nms.keepS[t] = w;
        }
    }
    gbar(barr, 3, b, G, b == 0);             // only block 0 (S6) consumes

    // ---------- S6: greedy NMS over active rows + finalize (block 0) ----------
    if (b == 0) {
        u32 flags = 0; int cnt = 0;
        {
            int r0 = 4 * t;
            #pragma unroll
            for (int q = 0; q < 4; q++) {
                int r = r0 + q;
                if (r < TOP_K && rflag[r]) { flags |= (1u << q); cnt++; }
            }
        }
        int x = cnt;
        for (int off = 1; off < 64; off <<= 1) {
            int v = __shfl_up(x, off, 64);
            if (lane >= off) x += v;
        }
        if (lane == 63) sh.nms.wsum[wv] = (u32)x;
        __syncthreads();
        int base = 0;
        for (int w = 0; w < wv; w++) base += (int)sh.nms.wsum[w];
        int pos = base + x - cnt;
        {
            int r0 = 4 * t;
            #pragma unroll
            for (int q = 0; q < 4; q++)
                if (flags & (1u << q)) sh.nms.act[pos++] = r0 + q;
        }
        if (t == 0) {
            int na = 0;
            for (int w = 0; w < 4; w++) na += (int)sh.nms.wsum[w];
            sh.nms.nactS = na;
        }
        __syncthreads();
        int nact = sh.nms.nactS;
        int nchunks = (nact + NMS_CHUNK - 1) / NMS_CHUNK;

        // Double-buffered chunked greedy with register-prefetched mask rows.
        if (nchunks > 0) {
            int cn0 = (nact < NMS_CHUNK) ? nact : NMS_CHUNK;
            for (int i = t; i < cn0 * 16; i += 256) {
                int row = sh.nms.act[i >> 4];
                sh.nms.Ml[i] = M[(size_t)row * 16 + (i & 15)];
            }
        }
        __syncthreads();
        u64 kp = (wv == 0 && lane < 16) ? sh.nms.keepS[lane] : 0ull;
        for (int ci = 0; ci < nchunks; ci++) {
            int c0 = ci * NMS_CHUNK;
            int cn = (nact - c0 < NMS_CHUNK) ? (nact - c0) : NMS_CHUNK;
            int cur = (ci & 1) * (NMS_CHUNK * 16);
            if (ci + 1 < nchunks && t >= 64) {
                int c0n = c0 + NMS_CHUNK;
                int cnn = (nact - c0n < NMS_CHUNK) ? (nact - c0n) : NMS_CHUNK;
                int nxt = ((ci + 1) & 1) * (NMS_CHUNK * 16);
                for (int i = t - 64; i < cnn * 16; i += 192) {
                    int row = sh.nms.act[c0n + (i >> 4)];
                    sh.nms.Ml[nxt + i] = M[(size_t)row * 16 + (i & 15)];
                }
            }
            if (wv == 0) {
                u64 mreg = (lane < 16 && cn > 0) ? sh.nms.Ml[cur + lane] : 0ull;
                for (int k = 0; k < cn; k++) {
                    u64 mnx = (lane < 16 && k + 1 < cn)
                            ? sh.nms.Ml[cur + (k + 1) * 16 + lane] : 0ull;
                    int i = sh.nms.act[c0 + k];
                    u64 kw = __shfl(kp, i >> 6, 64);
                    if ((kw >> (i & 63)) & 1ull) kp &= ~mreg;
                    mreg = mnx;
                }
            }
            __syncthreads();
        }
        if (wv == 0 && lane < 16) sh.nms.keepS[lane] = kp;
        __syncthreads();

        if (t == 0) {
            int cnt2 = 0;
            for (int w = 0; w < 16 && cnt2 < MAX_DET; w++) {
                u64 kw = sh.nms.keepS[w];
                while (kw && cnt2 < MAX_DET) {
                    int bbit = __ffsll((unsigned long long)kw) - 1;
                    sh.nms.det[cnt2++] = w * 64 + bbit;
                    kw &= kw - 1;
                }
            }
            for (; cnt2 < MAX_DET; cnt2++) sh.nms.det[cnt2] = -1;
        }
        __syncthreads();
        if (t < MAX_DET) {
            int i = sh.nms.det[t];
            if (i >= 0) {
                u32 a = sidx[i];
                const float* p = cls + (size_t)a * C;
                float best = -1e30f; int bc = 0;
                if (C == 80) {
                    #pragma unroll
                    for (int c4 = 0; c4 < 20; c4++) {
                        float4 v = *(const float4*)(p + c4 * 4);
                        if (v.x > best) { best = v.x; bc = c4 * 4; }
                        if (v.y > best) { best = v.y; bc = c4 * 4 + 1; }
                        if (v.z > best) { best = v.z; bc = c4 * 4 + 2; }
                        if (v.w > best) { best = v.w; bc = c4 * 4 + 3; }
                    }
                } else {
                    best = p[0]; bc = 0;
                    for (int c = 1; c < C; c++) {
                        float v = p[c];
                        if (v > best) { best = v; bc = c; }
                    }
                }
                out[t] = best;
                out[MAX_DET + t] = (float)bc;
                out[2 * MAX_DET + t * 4 + 0] = cbox[i * 4 + 0];
                out[2 * MAX_DET + t * 4 + 1] = cbox[i * 4 + 1];
                out[2 * MAX_DET + t * 4 + 2] = cbox[i * 4 + 2];
                out[2 * MAX_DET + t * 4 + 3] = cbox[i * 4 + 3];
            } else {
                out[t] = 0.0f;
                out[MAX_DET + t] = -1.0f;
                out[2 * MAX_DET + t * 4 + 0] = 0.0f;
                out[2 * MAX_DET + t * 4 + 1] = 0.0f;
                out[2 * MAX_DET + t * 4 + 2] = 0.0f;
                out[2 * MAX_DET + t * 4 + 3] = 0.0f;
            }
        }
    }
}

extern "C" void kernel_launch(void* const* d_in, const int* in_sizes, int n_in,
                              void* d_out, int out_size, void* d_ws, size_t ws_size,
                              hipStream_t stream) {
    (void)n_in; (void)out_size; (void)ws_size;
    const float* cls     = (const float*)d_in[0];
    const float* regs    = (const float*)d_in[1];
    const float* anchors = (const float*)d_in[2];
    const int*   pH      = (const int*)d_in[3];
    const int*   pW      = (const int*)d_in[4];
    int A = in_sizes[1] / 4;
    int C = in_sizes[0] / A;

    // grid = 2 blocks/CU, capped at 512 (flag-row capacity):
    // co-residency guaranteed (37.6KB LDS -> 2 blocks/CU, launch_bounds(256,2)).
    // R12 probe: 4 blocks/CU for S1 was null -> this is the measured optimum.
    static int nCU = 0;
    if (nCU <= 0) {
        int dev = 0;
        hipGetDevice(&dev);
        hipDeviceGetAttribute(&nCU, hipDeviceAttributeMultiprocessorCount, dev);
        if (nCU <= 0) nCU = 256;
    }
    int G = 2 * nCU;
    if (G > 512) G = 512;
    if (G < 8) G = 8;

    char* ws = (char*)d_ws;
    // Zero hist + state + barrier flags in one memset; the fill dispatch's
    // completion makes the zeros coherence-point visible.
    hipMemsetAsync(ws, 0, MEMSET_LEN, stream);
    mega<<<dim3(G), dim3(256), 0, stream>>>(cls, regs, anchors, pH, pW, A, C,
                                            ws, (float*)d_out);
}